// Round 2
// baseline (633.125 us; speedup 1.0000x reference)
//
#include <hip/hip_runtime.h>
#include <hip/hip_fp16.h>

// ---- problem constants ----
#define BTOK  4096
#define D_IN  1024
#define D_HID 4096
#define D_OUT 1024
#define NE    8
#define PT_MAX 80          // max padded 128-tiles (expert segments padded to 256 now)
#define PT2_MAX 40         // 256-row chunks
#define P_MAX  10240       // PT_MAX*128
#define KT1   32           // gemm1 K-chunks of 32 (1024/32)
#define NT1M  32           // gemm1 N 128-chunks (4096/128)
#define KT2C  128          // gemm2 K-chunks of 32 (4096/32)
#define NT2   8            // gemm2 N 128-chunks (1024/128)
#define GB    256          // gating blocks

typedef _Float16 half8 __attribute__((ext_vector_type(8)));
typedef _Float16 half4v __attribute__((ext_vector_type(4)));
typedef float    floatx4 __attribute__((ext_vector_type(4)));

// ---- ws layout (bytes), total ~260 MiB (512 MiB available) ----
// xt   : f16 x tiles   [80][32][128x32]      @ 0            (20,971,520)
// W1t  : f16 W1 tiles  [8][32][32][128x32]   @ 20,971,520   (67,108,864)
// W2t  : f16 W2 tiles  [8][8][128][128x32]   @ 88,080,384   (67,108,864)
// ht   : f16 h tiles   [80][128][128x32]     @ 155,189,248  (83,886,080)
// y    : f16 y         [10240][1024]         @ 239,075,328  (20,971,520)
// t2i  : int [8192]                          @ 260,046,848  (32,768)
// t2w  : f32 [8192]                          @ 260,079,616  (32,768)
// ptok : int [10240]                         @ 260,112,384  (40,960)
// pslot: int [8192]                          @ 260,153,344  (32,768)
// meta : cnt8,cur8,offs8,tile2e80,ntiles@104 @ 260,186,112  (512)
// pcnt : int  [256*8]                        @ 260,186,624  (8,192)
// pusage: f32 [256*8]                        @ 260,194,816  (8,192)

__device__ __forceinline__ void g2l16(const void* g, void* s) {
    __builtin_amdgcn_global_load_lds((const __attribute__((address_space(1))) void*)g,
                                     (__attribute__((address_space(3))) void*)s, 16, 0, 0);
}

// ---------------- gating: fp64 logits, top-2, softmax; LDS-aggregated partials ----------------
__global__ __launch_bounds__(256)
void gating_kernel(const float* __restrict__ x, const float* __restrict__ Wg,
                   const float* __restrict__ bg,
                   int* __restrict__ t2i, float* __restrict__ t2w,
                   int* __restrict__ pcnt, float* __restrict__ pusage) {
    __shared__ float wgT[NE * 1024];   // transposed gate weights: [e][i]
    __shared__ float susage[NE];
    __shared__ int   scnt[NE];
    int tid = threadIdx.x;
    if (tid < NE) { susage[tid] = 0.f; scnt[tid] = 0; }
    #pragma unroll
    for (int k = 0; k < 8192; k += 256) {
        int idx = k + tid;
        wgT[(idx & 7) * 1024 + (idx >> 3)] = Wg[idx];
    }
    __syncthreads();
    int wv = tid >> 6, lane = tid & 63;
    for (int tt = 0; tt < 4; ++tt) {
        int t = blockIdx.x * 16 + wv * 4 + tt;
        double part[NE];
        #pragma unroll
        for (int e = 0; e < NE; ++e) part[e] = 0.0;
        #pragma unroll
        for (int j = 0; j < 16; ++j) {
            int i = j * 64 + lane;
            double xv = (double)x[(size_t)t * D_IN + i];
            #pragma unroll
            for (int e = 0; e < NE; ++e) part[e] += xv * (double)wgT[e * 1024 + i];
        }
        #pragma unroll
        for (int e = 0; e < NE; ++e) {
            #pragma unroll
            for (int s = 32; s > 0; s >>= 1) part[e] += __shfl_xor(part[e], s, 64);
        }
        if (lane == 0) {
            float l[NE];
            #pragma unroll
            for (int e = 0; e < NE; ++e) l[e] = (float)part[e] + bg[e];
            float M = l[0];
            #pragma unroll
            for (int e = 1; e < NE; ++e) M = fmaxf(M, l[e]);
            float s = 0.f, g[NE];
            #pragma unroll
            for (int e = 0; e < NE; ++e) { g[e] = __expf(l[e] - M); s += g[e]; }
            float inv = 1.f / s;
            #pragma unroll
            for (int e = 0; e < NE; ++e) atomicAdd(&susage[e], g[e] * inv);
            int i0 = 0; float b0 = l[0];
            #pragma unroll
            for (int e = 1; e < NE; ++e) if (l[e] > b0) { b0 = l[e]; i0 = e; }
            int i1 = -1; float b1v = -1e30f;
            #pragma unroll
            for (int e = 0; e < NE; ++e) if (e != i0 && l[e] > b1v) { b1v = l[e]; i1 = e; }
            float w0 = 1.f / (1.f + expf(b1v - b0));
            t2i[2 * t] = i0; t2i[2 * t + 1] = i1;
            t2w[2 * t] = w0; t2w[2 * t + 1] = 1.f - w0;
            atomicAdd(&scnt[i0], 1);
            atomicAdd(&scnt[i1], 1);
        }
    }
    __syncthreads();
    if (tid < NE) {
        pcnt[blockIdx.x * NE + tid] = scnt[tid];
        pusage[blockIdx.x * NE + tid] = susage[tid];
    }
}

// ---------------- scan: reduce partials, 256-padded offsets, tile->expert map, loss ----------------
__global__ void scan_kernel(const int* __restrict__ pcnt, const float* __restrict__ pusage,
                            int* __restrict__ meta, float* __restrict__ out_loss) {
    int lane = threadIdx.x;           // 64 threads
    int e = lane & 7, b0 = lane >> 3;
    int c = 0; float u = 0.f;
    for (int b = b0; b < GB; b += 8) { c += pcnt[b * 8 + e]; u += pusage[b * 8 + e]; }
    #pragma unroll
    for (int s = 8; s < 64; s <<= 1) { c += __shfl_xor(c, s, 64); u += __shfl_xor(u, s, 64); }
    int cAll[NE]; float uAll[NE];
    #pragma unroll
    for (int q = 0; q < NE; ++q) { cAll[q] = __shfl(c, q, 64); uAll[q] = __shfl(u, q, 64); }
    if (lane == 0) {
        int* cnt = meta; int* cursor = meta + 8; int* offs = meta + 16;
        int* tile2e = meta + 24; int* ntiles = meta + 104;
        int run = 0;
        for (int q = 0; q < NE; ++q) {
            cnt[q] = cAll[q];
            offs[q] = run; cursor[q] = run;
            // pad each expert segment to a multiple of 256 slots (BM=256 blocks
            // must be single-expert); ntl counted in 128-tiles, always even.
            int ntl = ((cAll[q] + 255) >> 8) << 1;
            int tb = run >> 7;
            for (int i = 0; i < ntl; ++i) tile2e[tb + i] = q;
            run += ntl << 7;
        }
        ntiles[0] = run >> 7;          // total 128-tiles (even)
        float loss = 0.f;
        for (int q = 0; q < NE; ++q) { float uu = uAll[q] / (float)BTOK; loss += uu * uu; }
        out_loss[0] = (float)NE * loss;
    }
}

// ---------------- fill padded slots with token 0 ----------------
__global__ void fill_kernel(int* __restrict__ ptok) {
    ptok[blockIdx.x * 256 + threadIdx.x] = 0;
}

// ---------------- scatter: LDS-aggregated slot assignment ----------------
__global__ void scatter_kernel(const int* __restrict__ t2i, int* __restrict__ cursor,
                               int* __restrict__ ptok, int* __restrict__ pslot) {
    __shared__ int lcnt[NE], base[NE];
    int tid = threadIdx.x;
    if (tid < NE) lcnt[tid] = 0;
    __syncthreads();
    int t = blockIdx.x * 256 + tid;
    int e0 = t2i[2 * t], e1 = t2i[2 * t + 1];
    int l0 = atomicAdd(&lcnt[e0], 1);
    int l1 = atomicAdd(&lcnt[e1], 1);
    __syncthreads();
    if (tid < NE) base[tid] = atomicAdd(&cursor[tid], lcnt[tid]);
    __syncthreads();
    int s0 = base[e0] + l0, s1 = base[e1] + l1;
    ptok[s0] = t; ptok[s1] = t;
    pslot[2 * t] = s0; pslot[2 * t + 1] = s1;
}

// ---------------- gather x into tiled fp16 [ptile][k0][128x32] ----------------
__global__ void gather_x_kernel(const float* __restrict__ x, const int* __restrict__ ptok,
                                _Float16* __restrict__ xt) {
    int k0 = blockIdx.x, ptile = blockIdx.y;
    int t = threadIdx.x;
    int m = t >> 1, kb = (t & 1) * 16;
    int tok = ptok[ptile * 128 + m];
    const float* src = x + (size_t)tok * D_IN + k0 * 32 + kb;
    float4 v0 = *(const float4*)(src);
    float4 v1 = *(const float4*)(src + 4);
    float4 v2 = *(const float4*)(src + 8);
    float4 v3 = *(const float4*)(src + 12);
    half8 o0, o1;
    o0[0]=(_Float16)v0.x; o0[1]=(_Float16)v0.y; o0[2]=(_Float16)v0.z; o0[3]=(_Float16)v0.w;
    o0[4]=(_Float16)v1.x; o0[5]=(_Float16)v1.y; o0[6]=(_Float16)v1.z; o0[7]=(_Float16)v1.w;
    o1[0]=(_Float16)v2.x; o1[1]=(_Float16)v2.y; o1[2]=(_Float16)v2.z; o1[3]=(_Float16)v2.w;
    o1[4]=(_Float16)v3.x; o1[5]=(_Float16)v3.y; o1[6]=(_Float16)v3.z; o1[7]=(_Float16)v3.w;
    _Float16* dst = xt + ((size_t)ptile * KT1 + k0) * 4096 + t * 16;
    *(half8*)dst = o0;
    *(half8*)(dst + 8) = o1;
}

// ---------------- W [e][Ktot][Ntot] f32 -> tiles [e][nt][k0][128x32] f16 ----------------
__global__ void wtile_kernel(const float* __restrict__ W, _Float16* __restrict__ Wt,
                             int Ktot, int Ntot, int KT, int NT) {
    int k0 = blockIdx.x, ntb = blockIdx.y, e = blockIdx.z;
    int t = threadIdx.x;
    int nl = t >> 1, kb = (t & 1) * 16;
    const float* src = W + ((size_t)e * Ktot + k0 * 32 + kb) * Ntot + ntb * 128 + nl;
    float v[16];
    #pragma unroll
    for (int j = 0; j < 16; ++j) v[j] = src[(size_t)j * Ntot];
    half8 o0, o1;
    #pragma unroll
    for (int j = 0; j < 8; ++j) { o0[j] = (_Float16)v[j]; o1[j] = (_Float16)v[j + 8]; }
    _Float16* dst = Wt + (((size_t)e * NT + ntb) * KT + k0) * 4096 + t * 16;
    *(half8*)dst = o0;
    *(half8*)(dst + 8) = o1;
}

// ======== 256x256 pipelined GEMM core (BK=64, 8 waves, counted vmcnt, raw barriers) ========
// LDS regions: LA[slot][khalf][sub(2)*4096], LB likewise. One region (A+B khalf) = what a
// phase's MFMA consumes. Protocol invariants:
//  - frag reads for phase P are ISSUED in phase P-1, completed by P-1's lgkmcnt(0)+barrier
//  - stage into region R happens at the START of the phase AFTER all waves' reads of R
//    completed (>= one barrier later)  -> WAR safe
//  - vmcnt(8) (never 0 mid-loop) before touching the next K-tile: leaves the 8 youngest
//    (next-next K-tile) loads in flight
template<int NKT>
__device__ __forceinline__ void gemm_core(
    const _Float16* __restrict__ Ab, const _Float16* __restrict__ Bb, size_t aS,
    _Float16 (&LA)[2][2][2 * 4096], _Float16 (&LB)[2][2][2 * 4096],
    int wave, int lane, floatx4 (&acc)[8][4])
{
    int wr = wave >> 2, wc = wave & 3;
    int lr = lane & 15, lq = lane >> 4;
    int go  = wave * 512 + lane * 8;
    int aro = wr * 4096;                          // A sub select
    int bro = (wc >> 1) * 4096 + (wc & 1) * 2048; // B sub + 64-row offset
    int fo  = lr * 32 + lq * 8;                   // per-lane frag offset

#define STG(kt, s, h) do { \
    const _Float16* ga_ = Ab + (size_t)((kt) * 2 + (h)) * 4096 + go; \
    const _Float16* gb_ = Bb + (size_t)((kt) * 2 + (h)) * 4096 + go; \
    g2l16(ga_,      &LA[s][h][wave * 512]); \
    g2l16(ga_ + aS, &LA[s][h][4096 + wave * 512]); \
    g2l16(gb_,      &LB[s][h][wave * 512]); \
    g2l16(gb_ + aS, &LB[s][h][4096 + wave * 512]); \
} while (0)

    half8 af[8], bf[4];

    // prologue: stage K-tiles 0,1; complete 0; preload frags (0, khalf0)
    STG(0, 0, 0); STG(0, 0, 1); STG(1, 1, 0); STG(1, 1, 1);
    asm volatile("s_waitcnt vmcnt(8)" ::: "memory");
    __builtin_amdgcn_s_barrier();
    {
        const _Float16* Ar = &LA[0][0][aro];
        const _Float16* Br = &LB[0][0][bro];
        #pragma unroll
        for (int mf = 0; mf < 8; ++mf) af[mf] = *(const half8*)(Ar + mf * 512 + fo);
        #pragma unroll
        for (int nf = 0; nf < 4; ++nf) bf[nf] = *(const half8*)(Br + nf * 512 + fo);
    }
    asm volatile("s_waitcnt lgkmcnt(0)" ::: "memory");
    __builtin_amdgcn_s_barrier();   // all waves' [0][0] reads complete -> staging it later is safe

    for (int kt = 0; kt < NKT; ++kt) {
        int s = kt & 1;
        bool st = (kt + 2 < NKT);

        // ---- phase (kt,0): MFMA with (kt,0) frags; read (kt,1) frags; stage (kt+2, khalf0)
        if (st) STG(kt + 2, s, 0);   // [s][0] fully read by all waves as of previous barrier
        {
            const _Float16* Ar = &LA[s][1][aro];
            const _Float16* Br = &LB[s][1][bro];
            __builtin_amdgcn_s_setprio(1);
            #pragma unroll
            for (int mf = 0; mf < 8; ++mf) {
                #pragma unroll
                for (int nf = 0; nf < 4; ++nf)
                    acc[mf][nf] = __builtin_amdgcn_mfma_f32_16x16x32_f16(af[mf], bf[nf], acc[mf][nf], 0, 0, 0);
                if (mf == 7) {
                    #pragma unroll
                    for (int nf = 0; nf < 4; ++nf) bf[nf] = *(const half8*)(Br + nf * 512 + fo);
                }
                af[mf] = *(const half8*)(Ar + mf * 512 + fo);
            }
            __builtin_amdgcn_s_setprio(0);
        }
        asm volatile("s_waitcnt lgkmcnt(0)" ::: "memory");
        __builtin_amdgcn_s_barrier();

        // ---- phase (kt,1): MFMA with (kt,1) frags; read (kt+1,0) frags; stage (kt+2, khalf1)
        if (st) STG(kt + 2, s, 1);   // [s][1] fully read by all waves as of the barrier above
        bool nx = (kt + 1 < NKT);
        if (nx) {
            if (st) { asm volatile("s_waitcnt vmcnt(8)" ::: "memory"); }  // K-tile kt+1 landed
            else    { asm volatile("s_waitcnt vmcnt(0)" ::: "memory"); }
        }
        {
            const _Float16* Ar = &LA[s ^ 1][0][aro];
            const _Float16* Br = &LB[s ^ 1][0][bro];
            __builtin_amdgcn_s_setprio(1);
            #pragma unroll
            for (int mf = 0; mf < 8; ++mf) {
                #pragma unroll
                for (int nf = 0; nf < 4; ++nf)
                    acc[mf][nf] = __builtin_amdgcn_mfma_f32_16x16x32_f16(af[mf], bf[nf], acc[mf][nf], 0, 0, 0);
                if (mf == 7 && nx) {
                    #pragma unroll
                    for (int nf2 = 0; nf2 < 4; ++nf2) bf[nf2] = *(const half8*)(Br + nf2 * 512 + fo);
                }
                if (nx) af[mf] = *(const half8*)(Ar + mf * 512 + fo);
            }
            __builtin_amdgcn_s_setprio(0);
        }
        asm volatile("s_waitcnt lgkmcnt(0)" ::: "memory");
        __builtin_amdgcn_s_barrier();
    }
#undef STG
}

// ---------------- GEMM1: ht = relu(xt @ W1t^T + b1), 256x256 blocks ----------------
__global__ __launch_bounds__(512, 2)
void gemm1_kernel(const _Float16* __restrict__ xt, const _Float16* __restrict__ W1t,
                  const float* __restrict__ b1, _Float16* __restrict__ ht,
                  const int* __restrict__ meta) {
    int mc = blockIdx.x;
    if (mc * 2 >= meta[104]) return;
    int nc = blockIdx.y;
    int e = meta[24 + mc * 2];

    __shared__ __align__(16) _Float16 LA[2][2][2 * 4096];
    __shared__ __align__(16) _Float16 LB[2][2][2 * 4096];

    int tid = threadIdx.x, wave = tid >> 6, lane = tid & 63;
    int wr = wave >> 2, wc = wave & 3;
    int lr = lane & 15, lq = lane >> 4;

    const _Float16* Ab = xt + (size_t)(mc * 2) * (KT1 * 4096);
    const _Float16* Bb = W1t + (size_t)(e * NT1M + nc * 2) * (KT1 * 4096);
    size_t aS = (size_t)KT1 * 4096;

    floatx4 acc[8][4] = {};
    gemm_core<16>(Ab, Bb, aS, LA, LB, wave, lane, acc);

    const float* b1e = b1 + (size_t)e * D_HID + nc * 256 + wc * 64;
    #pragma unroll
    for (int mf = 0; mf < 8; ++mf) {
        #pragma unroll
        for (int v = 0; v < 4; ++v) {
            int mm = wr * 128 + mf * 16 + lq * 4 + v;     // 0..255
            int ptile = mc * 2 + (mm >> 7);
            int ml = mm & 127;
            #pragma unroll
            for (int nf = 0; nf < 4; ++nf) {
                int hl = nc * 256 + wc * 64 + nf * 16 + lr;   // 0..4095
                float val = acc[mf][nf][v] + b1e[nf * 16 + lr];
                ht[((size_t)ptile * KT2C + (hl >> 5)) * 4096 + ml * 32 + (hl & 31)]
                    = (_Float16)fmaxf(val, 0.f);
            }
        }
    }
}

// ---------------- GEMM2: y = ht @ W2t^T, 256x256 blocks ----------------
__global__ __launch_bounds__(512, 2)
void gemm2_kernel(const _Float16* __restrict__ ht, const _Float16* __restrict__ W2t,
                  _Float16* __restrict__ y, const int* __restrict__ meta) {
    int mc = blockIdx.x;
    if (mc * 2 >= meta[104]) return;
    int nc = blockIdx.y;
    int e = meta[24 + mc * 2];

    __shared__ __align__(16) _Float16 LA[2][2][2 * 4096];
    __shared__ __align__(16) _Float16 LB[2][2][2 * 4096];

    int tid = threadIdx.x, wave = tid >> 6, lane = tid & 63;
    int wr = wave >> 2, wc = wave & 3;
    int lr = lane & 15, lq = lane >> 4;

    const _Float16* Ab = ht + (size_t)(mc * 2) * (KT2C * 4096);
    const _Float16* Bb = W2t + (size_t)(e * NT2 + nc * 2) * (KT2C * 4096);
    size_t aS = (size_t)KT2C * 4096;

    floatx4 acc[8][4] = {};
    gemm_core<64>(Ab, Bb, aS, LA, LB, wave, lane, acc);

    #pragma unroll
    for (int mf = 0; mf < 8; ++mf) {
        #pragma unroll
        for (int v = 0; v < 4; ++v) {
            int mm = wr * 128 + mf * 16 + lq * 4 + v;
            int row = mc * 256 + mm;
            #pragma unroll
            for (int nf = 0; nf < 4; ++nf) {
                int col = nc * 256 + wc * 64 + nf * 16 + lr;
                y[(size_t)row * D_OUT + col] = (_Float16)acc[mf][nf][v];
            }
        }
    }
}

// ---------------- combine: out[t] = sum_k w_k * (y[slot_k] + b2[e_k]) ----------------
__global__ void combine_kernel(const _Float16* __restrict__ y, const float* __restrict__ b2,
                               const int* __restrict__ t2i, const float* __restrict__ t2w,
                               const int* __restrict__ pslot, float* __restrict__ out) {
    int t = blockIdx.x;
    int c = threadIdx.x * 4;
    int e0 = t2i[2 * t], e1 = t2i[2 * t + 1];
    float w0 = t2w[2 * t], w1 = t2w[2 * t + 1];
    size_t s0 = (size_t)pslot[2 * t] * D_OUT + c;
    size_t s1 = (size_t)pslot[2 * t + 1] * D_OUT + c;
    half4v a0 = *(const half4v*)(y + s0);
    half4v a1 = *(const half4v*)(y + s1);
    float4 bias0 = *(const float4*)(b2 + (size_t)e0 * D_OUT + c);
    float4 bias1 = *(const float4*)(b2 + (size_t)e1 * D_OUT + c);
    float4 o;
    o.x = w0 * ((float)a0[0] + bias0.x) + w1 * ((float)a1[0] + bias1.x);
    o.y = w0 * ((float)a0[1] + bias0.y) + w1 * ((float)a1[1] + bias1.y);
    o.z = w0 * ((float)a0[2] + bias0.z) + w1 * ((float)a1[2] + bias1.z);
    o.w = w0 * ((float)a0[3] + bias0.w) + w1 * ((float)a1[3] + bias1.w);
    *(float4*)(out + (size_t)t * D_OUT + c) = o;
}

extern "C" void kernel_launch(void* const* d_in, const int* in_sizes, int n_in,
                              void* d_out, int out_size, void* d_ws, size_t ws_size,
                              hipStream_t stream) {
    const float* x  = (const float*)d_in[0];
    const float* Wg = (const float*)d_in[1];
    const float* bg = (const float*)d_in[2];
    const float* W1 = (const float*)d_in[3];
    const float* b1 = (const float*)d_in[4];
    const float* W2 = (const float*)d_in[5];
    const float* b2 = (const float*)d_in[6];
    float* out = (float*)d_out;

    char* ws = (char*)d_ws;
    _Float16* xt     = (_Float16*)(ws);
    _Float16* W1t    = (_Float16*)(ws + 20971520ull);
    _Float16* W2t    = (_Float16*)(ws + 88080384ull);
    _Float16* ht     = (_Float16*)(ws + 155189248ull);
    _Float16* y      = (_Float16*)(ws + 239075328ull);
    int*      t2i    = (int*)(ws + 260046848ull);
    float*    t2w    = (float*)(ws + 260079616ull);
    int*      ptok   = (int*)(ws + 260112384ull);
    int*      pslot  = (int*)(ws + 260153344ull);
    int*      meta   = (int*)(ws + 260186112ull);
    int*      pcnt   = (int*)(ws + 260186624ull);
    float*    pusage = (float*)(ws + 260194816ull);
    int* cursor = meta + 8;

    hipMemsetAsync(meta, 0, 512, stream);

    gating_kernel<<<GB, 256, 0, stream>>>(x, Wg, bg, t2i, t2w, pcnt, pusage);
    scan_kernel<<<1, 64, 0, stream>>>(pcnt, pusage, meta, out + (size_t)BTOK * D_OUT);
    fill_kernel<<<PT2_MAX, 256, 0, stream>>>(ptok);
    scatter_kernel<<<16, 256, 0, stream>>>(t2i, cursor, ptok, pslot);
    gather_x_kernel<<<dim3(KT1, PT_MAX), 256, 0, stream>>>(x, ptok, xt);

    wtile_kernel<<<dim3(KT1, NT1M, 8), 256, 0, stream>>>(W1, W1t, D_IN, D_HID, KT1, NT1M);
    wtile_kernel<<<dim3(KT2C, NT2, 8), 256, 0, stream>>>(W2, W2t, D_HID, D_OUT, KT2C, NT2);

    gemm1_kernel<<<dim3(PT2_MAX, 16), 512, 0, stream>>>(xt, W1t, b1, ht, meta);
    gemm2_kernel<<<dim3(PT2_MAX, 4), 512, 0, stream>>>(ht, W2t, y, meta);

    combine_kernel<<<BTOK, 256, 0, stream>>>(y, b2, t2i, t2w, pslot, out);
}